// Round 9
// baseline (58.468 us; speedup 1.0000x reference)
//
#include <hip/hip_runtime.h>

// Problem: N=8 prior blocks, B=4, C=256, H=W=64.
// V = concat(blocks, x) -> [9,4,256,64,64]
// GroupNorm(1 group) over (C,H,W) per (n,b); logits = <w, K> over c;
// softmax over n; out = sum_n attn * V.
//
// Key identity: logits = rstd*(S - mean*sum_wg) + sum_wgb
//   where S[n,b,hw] = sum_c (w[c]*gnw[c]) * V[n,b,c,hw]
//
// Two passes over V:
//   k1: stats (sum,sumsq) partials + channel-dot partials S_part.
//   k2: block = (b, 256-hw segment, 16-c chunk). Prologue: reduce stats;
//       logits+softmax fully in registers (thread t owns hw column t).
//       Main loop: wave streams 1KB-contiguous (n,c) rows, nt loads.
// Lessons: r4: 32B strips -> exact 2x HBM over-fetch. r5: 64B granules at
// 16KB stride -> 3.3 TB/s; need >=1KB contiguous per wave (6.4 TB/s).
// r7: parallel stat-reduce + register preload of first V planes -> -3us.
// r8: __builtin_nontemporal_load needs a NATIVE vector type, not float4.

typedef float float4n __attribute__((ext_vector_type(4)));

#define NPRI 8
#define N1   9
#define BB   4
#define CC   256
#define HWN  4096
#define CHW  (CC * HWN)          // 1048576
#define NB   (N1 * BB)           // 36
#define GN_EPS 1e-5f

// workspace layout (floats):
//   [0..2303]      psum[36][64]
//   [2304..4607]   psq [36][64]
//   [4608..)       S_part[4][36][4096] = 589824 floats
#define WS_PSUM   0
#define WS_PSQ    2304
#define WS_SPART  4608

// ---------------- kernel 1: stats + channel-dot partials ----------------
// grid = 36 (nb) * 4 (cq) * 16 (hwseg) = 2304 blocks (9 per CU),
// 256 threads = 4 c-groups (16 ch each) x 64 lanes (64 float4 = 256 floats).
__global__ __launch_bounds__(256, 4) void k1_stats(
        const float* __restrict__ blocks, const float* __restrict__ x,
        const float* __restrict__ w, const float* __restrict__ gnw,
        float* __restrict__ ws) {
    const int bid   = blockIdx.x;
    const int nb    = bid >> 6;          // 0..35
    const int rem   = bid & 63;
    const int cq    = rem >> 4;          // 0..3
    const int hwseg = rem & 15;          // 0..15
    const int t     = threadIdx.x;
    const int cg    = t >> 6;            // 0..3
    const int lane  = t & 63;

    const float* base = (nb < NPRI * BB)
        ? blocks + (size_t)nb * CHW
        : x + (size_t)(nb - NPRI * BB) * CHW;

    const int hw0 = hwseg * 256 + lane * 4;
    const int c0  = cq * 64 + cg * 16;

    float s0 = 0.f, s1 = 0.f, s2 = 0.f, s3 = 0.f;   // channel-dot partial
    float sum = 0.f, sq = 0.f;

    #pragma unroll 4
    for (int c = c0; c < c0 + 16; ++c) {
        const float4 v = *reinterpret_cast<const float4*>(base + (size_t)c * HWN + hw0);
        const float wg = w[c] * gnw[c];
        sum += v.x + v.y + v.z + v.w;
        sq  += v.x * v.x + v.y * v.y + v.z * v.z + v.w * v.w;
        s0 += wg * v.x; s1 += wg * v.y; s2 += wg * v.z; s3 += wg * v.w;
    }

    // combine 4 c-groups' channel-dot via LDS; cg0 writes final cq-partial
    __shared__ float4 sbuf[3][64];
    if (cg) sbuf[cg - 1][lane] = make_float4(s0, s1, s2, s3);
    __syncthreads();
    if (!cg) {
        #pragma unroll
        for (int g = 0; g < 3; ++g) {
            const float4 o = sbuf[g][lane];
            s0 += o.x; s1 += o.y; s2 += o.z; s3 += o.w;
        }
        float* Sp = ws + WS_SPART;
        *reinterpret_cast<float4*>(Sp + (size_t)(cq * NB + nb) * HWN + hw0) =
            make_float4(s0, s1, s2, s3);
    }

    // block-reduce sum/sq -> unique slot (no atomics)
    #pragma unroll
    for (int off = 32; off; off >>= 1) {
        sum += __shfl_down(sum, off);
        sq  += __shfl_down(sq, off);
    }
    __shared__ float red[8];
    if (lane == 0) { red[cg] = sum; red[4 + cg] = sq; }
    __syncthreads();
    if (t == 0) {
        const int slot = nb * 64 + rem;
        ws[WS_PSUM + slot] = red[0] + red[1] + red[2] + red[3];
        ws[WS_PSQ  + slot] = red[4] + red[5] + red[6] + red[7];
    }
}

// -------- kernel 2: fused stats-finalize + softmax + weighted sum --------
// grid = 4 (b) * 16 (hwseg of 256 hw) * 16 (c-chunk of 16) = 1024 blocks
// (4 per CU, one generation), 256 threads = 4 waves.
__global__ __launch_bounds__(256, 4) void k2_fused(
        const float* __restrict__ blocks, const float* __restrict__ x,
        const float* __restrict__ w, const float* __restrict__ gnw,
        const float* __restrict__ gnb,
        const float* __restrict__ ws, float* __restrict__ out) {
    const int bid   = blockIdx.x;
    const int b     = bid >> 8;          // 0..3
    const int hwseg = (bid >> 4) & 15;   // 0..15
    const int cch   = bid & 15;          // 0..15
    const int t     = threadIdx.x;
    const int wv    = t >> 6, lane = t & 63;

    const int hwbase = hwseg * 256;
    const int c0 = cch * 16;
    const int hw = hwbase + lane * 4;

    // ---- preload first 3 n-planes of V (issued before prologue; the
    // global loads complete while the prologue's L2 reads run) ----
    float4n pre[3][4];
    #pragma unroll
    for (int n = 0; n < 3; ++n) {
        const float* vb = blocks + (size_t)(n * BB + b) * CHW;  // n<3 < NPRI
        #pragma unroll
        for (int k = 0; k < 4; ++k)
            pre[n][k] = __builtin_nontemporal_load(
                reinterpret_cast<const float4n*>(
                    vb + (size_t)(c0 + wv + 4 * k) * HWN + hw));
    }

    __shared__ float red[8];
    __shared__ float swg_s, swgb_s;
    __shared__ float pred_s[NB][4], pred_q[NB][4];
    __shared__ float mean_s[NB], rstd_s[NB];
    __shared__ float attn_s[N1][256];

    // ---- swg = <w,gnw>, swgb = <w,gnb> (block reduce, C==256) ----
    {
        float p = w[t] * gnw[t];
        float q = w[t] * gnb[t];
        #pragma unroll
        for (int off = 32; off; off >>= 1) {
            p += __shfl_down(p, off);
            q += __shfl_down(q, off);
        }
        if (lane == 0) { red[wv] = p; red[4 + wv] = q; }
    }

    // ---- stats: 144 threads, each reduces 16 partials (4 per nb) ----
    if (t < NB * 4) {
        const int nb = t >> 2, j = t & 3;
        float s = 0.f, ss = 0.f;
        #pragma unroll 8
        for (int i = j * 16; i < j * 16 + 16; ++i) {
            s  += ws[WS_PSUM + nb * 64 + i];
            ss += ws[WS_PSQ  + nb * 64 + i];
        }
        pred_s[nb][j] = s;
        pred_q[nb][j] = ss;
    }
    __syncthreads();
    if (t < NB) {
        const float s  = pred_s[t][0] + pred_s[t][1] + pred_s[t][2] + pred_s[t][3];
        const float ss = pred_q[t][0] + pred_q[t][1] + pred_q[t][2] + pred_q[t][3];
        const float mean = s * (1.0f / CHW);
        const float var  = ss * (1.0f / CHW) - mean * mean;
        mean_s[t] = mean;
        rstd_s[t] = rsqrtf(var + GN_EPS);
    }
    if (t == 0) {
        swg_s  = red[0] + red[1] + red[2] + red[3];
        swgb_s = red[4] + red[5] + red[6] + red[7];
    }
    __syncthreads();

    // ---- logits + softmax fully in registers: thread t owns hw column
    // hwbase+t (coalesced 1KB S_part rows); single LDS write of attn ----
    {
        const float* Sp = ws + WS_SPART;
        const float swg = swg_s, swgb = swgb_s;
        float l[N1];
        float mx = -1e30f;
        #pragma unroll
        for (int n = 0; n < N1; ++n) {
            const int nb = n * BB + b;
            const size_t o = (size_t)nb * HWN + hwbase + t;
            const float S = Sp[o] + Sp[(size_t)NB * HWN + o]
                          + Sp[(size_t)2 * NB * HWN + o] + Sp[(size_t)3 * NB * HWN + o];
            l[n] = rstd_s[nb] * (S - mean_s[nb] * swg) + swgb;
            mx = fmaxf(mx, l[n]);
        }
        float den = 0.f;
        #pragma unroll
        for (int n = 0; n < N1; ++n) { l[n] = __expf(l[n] - mx); den += l[n]; }
        const float inv = 1.0f / den;
        #pragma unroll
        for (int n = 0; n < N1; ++n) attn_s[n][t] = l[n] * inv;
    }
    __syncthreads();

    // ---- weighted sum over n: wave wv streams (n, c) rows of 1KB ----
    float4n acc[4];
    #pragma unroll
    for (int k = 0; k < 4; ++k) acc[k] = (float4n)(0.f);

    // n = 0..2 from the preload registers
    #pragma unroll
    for (int n = 0; n < 3; ++n) {
        const float4n a = *reinterpret_cast<const float4n*>(&attn_s[n][lane * 4]);
        #pragma unroll
        for (int k = 0; k < 4; ++k)
            acc[k] += a * pre[n][k];
    }
    // n = 3..8 streamed with nontemporal loads (read-last; keep L2 clean)
    #pragma unroll
    for (int n = 3; n < N1; ++n) {
        const float* vb = (n < NPRI)
            ? blocks + (size_t)(n * BB + b) * CHW
            : x + (size_t)b * CHW;
        const float4n a = *reinterpret_cast<const float4n*>(&attn_s[n][lane * 4]);
        #pragma unroll
        for (int k = 0; k < 4; ++k) {
            const float4n v = __builtin_nontemporal_load(
                reinterpret_cast<const float4n*>(
                    vb + (size_t)(c0 + wv + 4 * k) * HWN + hw));
            acc[k] += a * v;
        }
    }

    #pragma unroll
    for (int k = 0; k < 4; ++k) {
        float* o = out + (size_t)(b * CC + c0 + wv + 4 * k) * HWN + hw;
        __builtin_nontemporal_store(acc[k].x, o + 0);
        __builtin_nontemporal_store(acc[k].y, o + 1);
        __builtin_nontemporal_store(acc[k].z, o + 2);
        __builtin_nontemporal_store(acc[k].w, o + 3);
    }
}

extern "C" void kernel_launch(void* const* d_in, const int* in_sizes, int n_in,
                              void* d_out, int out_size, void* d_ws, size_t ws_size,
                              hipStream_t stream) {
    const float* blocks = (const float*)d_in[0];
    const float* x      = (const float*)d_in[1];
    const float* w      = (const float*)d_in[2];
    const float* gnw    = (const float*)d_in[3];
    const float* gnb    = (const float*)d_in[4];
    float* out = (float*)d_out;
    float* ws  = (float*)d_ws;

    hipLaunchKernelGGL(k1_stats, dim3(2304), dim3(256), 0, stream, blocks, x, w, gnw, ws);
    hipLaunchKernelGGL(k2_fused, dim3(1024), dim3(256), 0, stream,
                       blocks, x, w, gnw, gnb, ws, out);
}

// Round 10
// 54.545 us; speedup vs baseline: 1.0719x; 1.0719x over previous
//
#include <hip/hip_runtime.h>

// Problem: N=8 prior blocks, B=4, C=256, H=W=64.
// V = concat(blocks, x) -> [9,4,256,64,64]
// GroupNorm(1 group) over (C,H,W) per (n,b); logits = <w, K> over c;
// softmax over n; out = sum_n attn * V.
//
// Key identity: logits = rstd*(S - mean*sum_wg) + sum_wgb
//   where S[n,b,hw] = sum_c (w[c]*gnw[c]) * V[n,b,c,hw]
//
// Two passes over V:
//   k1: stats (sum,sumsq) partials + channel-dot partials S_part.
//   k2: block = (b, 256-hw segment, 16-c chunk). Prologue: reduce stats;
//       logits+softmax fully in registers (thread t owns hw column t).
//       Main loop: wave streams 1KB-contiguous (n,c) rows.
// Lessons: r4: 32B strips -> exact 2x HBM over-fetch. r5: 64B granules at
// 16KB stride -> 3.3 TB/s; need >=1KB contiguous per wave (6.4 TB/s).
// r7: parallel stat-reduce + register preload of first V planes -> -3us.
// r8: __builtin_nontemporal_load needs a NATIVE vector type, not float4.
// r9: nt LOADS on V cost +4.5us — V is read twice (k1 then k2); nt bypasses
//     the L3 hits k2 was getting from k1's pass. nt loads only for
//     read-once data. nt stores on out are fine.

typedef float float4n __attribute__((ext_vector_type(4)));

#define NPRI 8
#define N1   9
#define BB   4
#define CC   256
#define HWN  4096
#define CHW  (CC * HWN)          // 1048576
#define NB   (N1 * BB)           // 36
#define GN_EPS 1e-5f

// workspace layout (floats):
//   [0..2303]      psum[36][64]
//   [2304..4607]   psq [36][64]
//   [4608..)       S_part[4][36][4096] = 589824 floats
#define WS_PSUM   0
#define WS_PSQ    2304
#define WS_SPART  4608

// ---------------- kernel 1: stats + channel-dot partials ----------------
// grid = 36 (nb) * 4 (cq) * 16 (hwseg) = 2304 blocks (9 per CU),
// 256 threads = 4 c-groups (16 ch each) x 64 lanes (64 float4 = 256 floats).
__global__ __launch_bounds__(256, 4) void k1_stats(
        const float* __restrict__ blocks, const float* __restrict__ x,
        const float* __restrict__ w, const float* __restrict__ gnw,
        float* __restrict__ ws) {
    const int bid   = blockIdx.x;
    const int nb    = bid >> 6;          // 0..35
    const int rem   = bid & 63;
    const int cq    = rem >> 4;          // 0..3
    const int hwseg = rem & 15;          // 0..15
    const int t     = threadIdx.x;
    const int cg    = t >> 6;            // 0..3
    const int lane  = t & 63;

    const float* base = (nb < NPRI * BB)
        ? blocks + (size_t)nb * CHW
        : x + (size_t)(nb - NPRI * BB) * CHW;

    const int hw0 = hwseg * 256 + lane * 4;
    const int c0  = cq * 64 + cg * 16;

    float s0 = 0.f, s1 = 0.f, s2 = 0.f, s3 = 0.f;   // channel-dot partial
    float sum = 0.f, sq = 0.f;

    #pragma unroll 4
    for (int c = c0; c < c0 + 16; ++c) {
        const float4 v = *reinterpret_cast<const float4*>(base + (size_t)c * HWN + hw0);
        const float wg = w[c] * gnw[c];
        sum += v.x + v.y + v.z + v.w;
        sq  += v.x * v.x + v.y * v.y + v.z * v.z + v.w * v.w;
        s0 += wg * v.x; s1 += wg * v.y; s2 += wg * v.z; s3 += wg * v.w;
    }

    // combine 4 c-groups' channel-dot via LDS; cg0 writes final cq-partial
    __shared__ float4 sbuf[3][64];
    if (cg) sbuf[cg - 1][lane] = make_float4(s0, s1, s2, s3);
    __syncthreads();
    if (!cg) {
        #pragma unroll
        for (int g = 0; g < 3; ++g) {
            const float4 o = sbuf[g][lane];
            s0 += o.x; s1 += o.y; s2 += o.z; s3 += o.w;
        }
        float* Sp = ws + WS_SPART;
        *reinterpret_cast<float4*>(Sp + (size_t)(cq * NB + nb) * HWN + hw0) =
            make_float4(s0, s1, s2, s3);
    }

    // block-reduce sum/sq -> unique slot (no atomics)
    #pragma unroll
    for (int off = 32; off; off >>= 1) {
        sum += __shfl_down(sum, off);
        sq  += __shfl_down(sq, off);
    }
    __shared__ float red[8];
    if (lane == 0) { red[cg] = sum; red[4 + cg] = sq; }
    __syncthreads();
    if (t == 0) {
        const int slot = nb * 64 + rem;
        ws[WS_PSUM + slot] = red[0] + red[1] + red[2] + red[3];
        ws[WS_PSQ  + slot] = red[4] + red[5] + red[6] + red[7];
    }
}

// -------- kernel 2: fused stats-finalize + softmax + weighted sum --------
// grid = 4 (b) * 16 (hwseg of 256 hw) * 16 (c-chunk of 16) = 1024 blocks
// (4 per CU, one generation), 256 threads = 4 waves.
__global__ __launch_bounds__(256, 4) void k2_fused(
        const float* __restrict__ blocks, const float* __restrict__ x,
        const float* __restrict__ w, const float* __restrict__ gnw,
        const float* __restrict__ gnb,
        const float* __restrict__ ws, float* __restrict__ out) {
    const int bid   = blockIdx.x;
    const int b     = bid >> 8;          // 0..3
    const int hwseg = (bid >> 4) & 15;   // 0..15
    const int cch   = bid & 15;          // 0..15
    const int t     = threadIdx.x;
    const int wv    = t >> 6, lane = t & 63;

    const int hwbase = hwseg * 256;
    const int c0 = cch * 16;
    const int hw = hwbase + lane * 4;

    // ---- preload first 3 n-planes of V (issued before prologue; the
    // global loads complete while the prologue's L2 reads run) ----
    float4n pre[3][4];
    #pragma unroll
    for (int n = 0; n < 3; ++n) {
        const float* vb = blocks + (size_t)(n * BB + b) * CHW;  // n<3 < NPRI
        #pragma unroll
        for (int k = 0; k < 4; ++k)
            pre[n][k] = *reinterpret_cast<const float4n*>(
                vb + (size_t)(c0 + wv + 4 * k) * HWN + hw);
    }

    __shared__ float red[8];
    __shared__ float swg_s, swgb_s;
    __shared__ float pred_s[NB][4], pred_q[NB][4];
    __shared__ float mean_s[NB], rstd_s[NB];
    __shared__ float attn_s[N1][256];

    // ---- swg = <w,gnw>, swgb = <w,gnb> (block reduce, C==256) ----
    {
        float p = w[t] * gnw[t];
        float q = w[t] * gnb[t];
        #pragma unroll
        for (int off = 32; off; off >>= 1) {
            p += __shfl_down(p, off);
            q += __shfl_down(q, off);
        }
        if (lane == 0) { red[wv] = p; red[4 + wv] = q; }
    }

    // ---- stats: 144 threads, each reduces 16 partials (4 per nb) ----
    if (t < NB * 4) {
        const int nb = t >> 2, j = t & 3;
        float s = 0.f, ss = 0.f;
        #pragma unroll 8
        for (int i = j * 16; i < j * 16 + 16; ++i) {
            s  += ws[WS_PSUM + nb * 64 + i];
            ss += ws[WS_PSQ  + nb * 64 + i];
        }
        pred_s[nb][j] = s;
        pred_q[nb][j] = ss;
    }
    __syncthreads();
    if (t < NB) {
        const float s  = pred_s[t][0] + pred_s[t][1] + pred_s[t][2] + pred_s[t][3];
        const float ss = pred_q[t][0] + pred_q[t][1] + pred_q[t][2] + pred_q[t][3];
        const float mean = s * (1.0f / CHW);
        const float var  = ss * (1.0f / CHW) - mean * mean;
        mean_s[t] = mean;
        rstd_s[t] = rsqrtf(var + GN_EPS);
    }
    if (t == 0) {
        swg_s  = red[0] + red[1] + red[2] + red[3];
        swgb_s = red[4] + red[5] + red[6] + red[7];
    }
    __syncthreads();

    // ---- logits + softmax fully in registers: thread t owns hw column
    // hwbase+t (coalesced 1KB S_part rows); single LDS write of attn ----
    {
        const float* Sp = ws + WS_SPART;
        const float swg = swg_s, swgb = swgb_s;
        float l[N1];
        float mx = -1e30f;
        #pragma unroll
        for (int n = 0; n < N1; ++n) {
            const int nb = n * BB + b;
            const size_t o = (size_t)nb * HWN + hwbase + t;
            const float S = Sp[o] + Sp[(size_t)NB * HWN + o]
                          + Sp[(size_t)2 * NB * HWN + o] + Sp[(size_t)3 * NB * HWN + o];
            l[n] = rstd_s[nb] * (S - mean_s[nb] * swg) + swgb;
            mx = fmaxf(mx, l[n]);
        }
        float den = 0.f;
        #pragma unroll
        for (int n = 0; n < N1; ++n) { l[n] = __expf(l[n] - mx); den += l[n]; }
        const float inv = 1.0f / den;
        #pragma unroll
        for (int n = 0; n < N1; ++n) attn_s[n][t] = l[n] * inv;
    }
    __syncthreads();

    // ---- weighted sum over n: wave wv streams (n, c) rows of 1KB ----
    float4n acc[4];
    #pragma unroll
    for (int k = 0; k < 4; ++k) acc[k] = (float4n)(0.f);

    // n = 0..2 from the preload registers
    #pragma unroll
    for (int n = 0; n < 3; ++n) {
        const float4n a = *reinterpret_cast<const float4n*>(&attn_s[n][lane * 4]);
        #pragma unroll
        for (int k = 0; k < 4; ++k)
            acc[k] += a * pre[n][k];
    }
    // n = 3..8 streamed (normal loads: V was cached by k1's pass — r9 lesson)
    #pragma unroll
    for (int n = 3; n < N1; ++n) {
        const float* vb = (n < NPRI)
            ? blocks + (size_t)(n * BB + b) * CHW
            : x + (size_t)b * CHW;
        const float4n a = *reinterpret_cast<const float4n*>(&attn_s[n][lane * 4]);
        #pragma unroll
        for (int k = 0; k < 4; ++k) {
            const float4n v = *reinterpret_cast<const float4n*>(
                vb + (size_t)(c0 + wv + 4 * k) * HWN + hw);
            acc[k] += a * v;
        }
    }

    #pragma unroll
    for (int k = 0; k < 4; ++k) {
        float* o = out + (size_t)(b * CC + c0 + wv + 4 * k) * HWN + hw;
        __builtin_nontemporal_store(acc[k].x, o + 0);
        __builtin_nontemporal_store(acc[k].y, o + 1);
        __builtin_nontemporal_store(acc[k].z, o + 2);
        __builtin_nontemporal_store(acc[k].w, o + 3);
    }
}

extern "C" void kernel_launch(void* const* d_in, const int* in_sizes, int n_in,
                              void* d_out, int out_size, void* d_ws, size_t ws_size,
                              hipStream_t stream) {
    const float* blocks = (const float*)d_in[0];
    const float* x      = (const float*)d_in[1];
    const float* w      = (const float*)d_in[2];
    const float* gnw    = (const float*)d_in[3];
    const float* gnb    = (const float*)d_in[4];
    float* out = (float*)d_out;
    float* ws  = (float*)d_ws;

    hipLaunchKernelGGL(k1_stats, dim3(2304), dim3(256), 0, stream, blocks, x, w, gnw, ws);
    hipLaunchKernelGGL(k2_fused, dim3(1024), dim3(256), 0, stream,
                       blocks, x, w, gnw, gnb, ws, out);
}